// Round 1
// 519.249 us; speedup vs baseline: 1.0340x; 1.0340x over previous
//
#include <hip/hip_runtime.h>
#include <math.h>

// out_b = E * x_b * E^T per batch, E = D@D, D[k][j] = 2 cos(pi*k*(2j+1)/512).
// Fully fused: one block per batch, W = E*x_b kept in LDS (bf16, XOR-swizzled),
// so HBM traffic is just X-read + OUT-write (~512 MiB total).

typedef __bf16 bf16x8 __attribute__((ext_vector_type(8)));
typedef float f32x4 __attribute__((ext_vector_type(4)));
typedef unsigned int u32x2 __attribute__((ext_vector_type(2)));
typedef unsigned int u32x4 __attribute__((ext_vector_type(4)));

__device__ __forceinline__ unsigned short f2bf(float f) {
  unsigned u = __builtin_bit_cast(unsigned, f);
  u += 0x7fffu + ((u >> 16) & 1u);  // round-to-nearest-even (finite inputs)
  return (unsigned short)(u >> 16);
}

__device__ __forceinline__ unsigned pack2(float a, float b) {
  return (unsigned)f2bf(a) | ((unsigned)f2bf(b) << 16);
}

// D[i][j] = 2 cos(pi * i * (2j+1) / 512); exact integer angle reduction mod 1024.
__global__ void k_dmat(float* __restrict__ D) {
  const int i = blockIdx.x, j = threadIdx.x;
  const int m = (i * (2 * j + 1)) & 1023;
  D[(i << 8) + j] = 2.0f * cosf((float)m * 6.135923151542565e-3f);  // pi/512
}

// E = D @ D, stored as bf16 bits (row-major 256x256).
__global__ void k_emat(const float* __restrict__ D, unsigned short* __restrict__ E) {
  const int i = blockIdx.x, j = threadIdx.x;
  const float* Di = D + (i << 8);
  float acc = 0.0f;
  for (int m = 0; m < 256; ++m) acc = fmaf(Di[m], D[(m << 8) + j], acc);
  E[(i << 8) + j] = f2bf(acc);
}

// One block per batch: phase 1 W = E*x (W^T-layout MFMA -> packed b64 LDS
// writes), phase 2 OUT = W*E^T (out^T-layout MFMA -> dwordx4 global stores).
__global__ __launch_bounds__(512, 2) void k_fused(
    const unsigned short* __restrict__ E, const float* __restrict__ X,
    float* __restrict__ OUT) {
  __shared__ __align__(16) unsigned short Wl[256 * 256];  // 128 KiB, swizzled rows
  __shared__ __align__(16) unsigned short xb[64 * 256];   // 32 KiB, frag order

  const int b = blockIdx.x;
  const int t = threadIdx.x;
  const int l = t & 63, w = t >> 6;
  const int lr = l & 15, lq = l >> 4;
  const int wm = w >> 2;  // m-half (phase 1 & 2)
  const int wc = w & 3;   // c-quarter (ph1) / n-quarter (ph2)

  // x staging: wave w loads rows w*8+i of the strip; lane l loads cols l*4..+3.
  const float* Xb = X + ((size_t)b << 16) + (w << 11) + (l << 2);
  // fragment-order write slot: frag=(l>>2)*2+(w>>2), cell=(w&3)*16+(l&3)*4+c
  u32x4* xw = ((u32x4*)xb) + ((((l >> 2) << 1) + (w >> 2)) << 6) +
              ((w & 3) << 4) + ((l & 3) << 2);
  // E fragment bases (global; E is L2-hot everywhere)
  const unsigned short* Em = E + (((wm << 7) + lr) << 8) + (lq << 3);
  const unsigned short* En = E + (((wc << 6) + lr) << 8) + (lq << 3);

  f32x4 acc[8][4];
#pragma unroll
  for (int a = 0; a < 8; ++a)
#pragma unroll
    for (int c = 0; c < 4; ++c)
#pragma unroll
      for (int e = 0; e < 4; ++e) acc[a][c][e] = 0.0f;

  // ---------------- phase 1: W = E * x_b (computed as W^T tiles) ----------
  f32x4 xv[2][8];
#pragma unroll
  for (int i = 0; i < 8; ++i) xv[0][i] = *(const f32x4*)(Xb + (i << 8));

#pragma unroll
  for (int kt = 0; kt < 4; ++kt) {
    const int cur = kt & 1;
    if (kt) {  // previous strip's LDS reads are complete at each wave's barrier
      asm volatile("" ::: "memory");
      __builtin_amdgcn_s_barrier();
      asm volatile("" ::: "memory");
    }
    // pack fp32 -> bf16 pairs along k and write in MFMA fragment order
#pragma unroll
    for (int c = 0; c < 4; ++c) {
      u32x4 p;
      p.x = pack2(xv[cur][0][c], xv[cur][1][c]);
      p.y = pack2(xv[cur][2][c], xv[cur][3][c]);
      p.z = pack2(xv[cur][4][c], xv[cur][5][c]);
      p.w = pack2(xv[cur][6][c], xv[cur][7][c]);
      xw[c] = p;
    }
    // T14: issue next strip's global loads before the barrier stall
    if (kt < 3) {
      const float* xg = Xb + ((kt + 1) << 14);
#pragma unroll
      for (int i = 0; i < 8; ++i) xv[cur ^ 1][i] = *(const f32x4*)(xg + (i << 8));
    }
    asm volatile("s_waitcnt lgkmcnt(0)" ::: "memory");  // own ds_writes done
    __builtin_amdgcn_s_barrier();                       // no vmcnt drain!
    asm volatile("" ::: "memory");
#pragma unroll
    for (int ks = 0; ks < 2; ++ks) {
      bf16x8 bx[4], ef[8];
#pragma unroll
      for (int tc = 0; tc < 4; ++tc)
        bx[tc] = ((const bf16x8*)xb)[(((((wc << 2) + tc) << 1) + ks) << 6) + l];
#pragma unroll
      for (int tm = 0; tm < 8; ++tm)
        ef[tm] = *(const bf16x8*)(Em + (tm << 12) + (kt << 6) + (ks << 5));
      // swapped operands: A = x^T frag, B = E frag  ->  D = W^T tile
#pragma unroll
      for (int tm = 0; tm < 8; ++tm)
#pragma unroll
        for (int tc = 0; tc < 4; ++tc)
          acc[tm][tc] = __builtin_amdgcn_mfma_f32_16x16x32_bf16(
              bx[tc], ef[tm], acc[tm][tc], 0, 0, 0);
    }
  }

  // W epilogue: lane holds W[wm*128+tm*16+lr][wc*64+tc*16+lq*4 + r], r=0..3
  // -> 4 contiguous cols per lane -> packed 8B LDS writes, XOR-swizzled rows.
#pragma unroll
  for (int tm = 0; tm < 8; ++tm) {
    const int row = (wm << 7) + (tm << 4) + lr;
    char* rowp = (char*)Wl + (row << 9);
    const int swz = (row & 7) << 4;
#pragma unroll
    for (int tc = 0; tc < 4; ++tc) {
      u32x2 pw;
      pw.x = pack2(acc[tm][tc][0], acc[tm][tc][1]);
      pw.y = pack2(acc[tm][tc][2], acc[tm][tc][3]);
      const int coff = (wc << 7) + (tc << 5) + (lq << 3);
      *(u32x2*)(rowp + (coff ^ swz)) = pw;
    }
  }
  asm volatile("s_waitcnt lgkmcnt(0)" ::: "memory");
  __builtin_amdgcn_s_barrier();
  asm volatile("" ::: "memory");

  // ---------------- phase 2: OUT = W * E^T (computed as out^T tiles) ------
#pragma unroll
  for (int a = 0; a < 8; ++a)
#pragma unroll
    for (int c = 0; c < 4; ++c)
#pragma unroll
      for (int e = 0; e < 4; ++e) acc[a][c][e] = 0.0f;

#pragma unroll
  for (int kt = 0; kt < 4; ++kt) {
#pragma unroll
    for (int ks = 0; ks < 2; ++ks) {
      bf16x8 wf[8], ef[4];
#pragma unroll
      for (int tm = 0; tm < 8; ++tm) {
        const int row = (wm << 7) + (tm << 4) + lr;
        const int koff = (kt << 7) + (ks << 6) + (lq << 4);
        wf[tm] = *(const bf16x8*)((const char*)Wl + (row << 9) +
                                  (koff ^ ((row & 7) << 4)));
      }
#pragma unroll
      for (int tn = 0; tn < 4; ++tn)
        ef[tn] = *(const bf16x8*)(En + (tn << 12) + (kt << 6) + (ks << 5));
      // swapped operands: A = E frag (rows n), B = W frag -> D = out^T tile
#pragma unroll
      for (int tm = 0; tm < 8; ++tm)
#pragma unroll
        for (int tn = 0; tn < 4; ++tn)
          acc[tm][tn] = __builtin_amdgcn_mfma_f32_16x16x32_bf16(
              ef[tn], wf[tm], acc[tm][tn], 0, 0, 0);
    }
  }

  // lane holds out[wm*128+tm*16+lr][wc*64+tn*16+lq*4 + r] -> dwordx4 stores
  float* Ob = OUT + ((size_t)b << 16);
#pragma unroll
  for (int tm = 0; tm < 8; ++tm) {
    float* rowp = Ob + (((wm << 7) + (tm << 4) + lr) << 8) + (wc << 6) + (lq << 2);
#pragma unroll
    for (int tn = 0; tn < 4; ++tn)
      *(f32x4*)(rowp + (tn << 4)) = acc[tm][tn];
  }
}

extern "C" void kernel_launch(void* const* d_in, const int* in_sizes, int n_in,
                              void* d_out, int out_size, void* d_ws, size_t ws_size,
                              hipStream_t stream) {
  (void)in_sizes; (void)n_in; (void)out_size; (void)ws_size;
  const float* X = (const float*)d_in[0];
  float* OUT = (float*)d_out;
  char* ws = (char*)d_ws;
  float* D = (float*)ws;                                    // 256 KiB
  unsigned short* E = (unsigned short*)(ws + (256 * 1024)); // 128 KiB

  k_dmat<<<dim3(256), dim3(256), 0, stream>>>(D);
  k_emat<<<dim3(256), dim3(256), 0, stream>>>(D, E);
  k_fused<<<dim3(1024), dim3(512), 0, stream>>>(E, X, OUT);
}